// Round 1
// baseline (170.407 us; speedup 1.0000x reference)
//
#include <hip/hip_runtime.h>
#include <hip/hip_bf16.h>

typedef __bf16 bf16;
typedef __bf16 bf16x4 __attribute__((ext_vector_type(4)));
typedef __bf16 bf16x8 __attribute__((ext_vector_type(8)));
typedef float  f32x4  __attribute__((ext_vector_type(4)));

#define BSZ   256
#define SEQ   256
#define DIN   512
#define DEMB  1024
#define KSEL  76
#define MROWS (BSZ * KSEL)   // 19456
#define MTILES (MROWS / 128) // 152

__device__ __forceinline__ void gload16(const void* g, void* l) {
  __builtin_amdgcn_global_load_lds((const __attribute__((address_space(1))) void*)g,
                                   (__attribute__((address_space(3))) void*)l, 16, 0, 0);
}

// ---- K0: token lengths -> closed-form top-k indices + pool lengths ----
// atten_sel[b,s] = -1 (s<len) / -0.0 (s>=len); lax.top_k ties -> lowest index
// first. So topk order = [len..255] then [0..] up to k=76.
__global__ void k_prep(const int* __restrict__ text, int* __restrict__ topk,
                       int* __restrict__ plen) {
  int b = blockIdx.x, t = threadIdx.x;
  __shared__ int red[256];
  red[t] = (text[b * SEQ + t] != 0) ? 1 : 0;
  __syncthreads();
  for (int s = 128; s > 0; s >>= 1) {
    if (t < s) red[t] += red[t + s];
    __syncthreads();
  }
  int len = red[0];
  int z = SEQ - len;  // count of -0.0 entries
  if (t < KSEL) topk[b * KSEL + t] = (t < z) ? (len + t) : (t - z);
  if (t == 0) {
    int p = len - 2;
    p = p < 1 ? 1 : (p > KSEL ? KSEL : p);
    plen[b] = p;
  }
}

// ---- weight transpose f32 (K x N) -> bf16 (N x K), row stride ldo ----
__global__ void k_transpose(const float* __restrict__ W, bf16* __restrict__ Wt,
                            int N, int ldo) {
  __shared__ float tile[32][33];
  int tx = threadIdx.x, ty = threadIdx.y;
  int n = blockIdx.x * 32 + tx;
  int k0 = blockIdx.y * 32;
#pragma unroll
  for (int r = 0; r < 32; r += 8)
    tile[ty + r][tx] = W[(size_t)(k0 + ty + r) * N + n];
  __syncthreads();
#pragma unroll
  for (int r = 0; r < 32; r += 8)
    Wt[(size_t)(blockIdx.x * 32 + ty + r) * ldo + k0 + tx] = (bf16)tile[tx][ty + r];
}

__global__ void k_bias2(const float* __restrict__ a, const float* __restrict__ b,
                        float* __restrict__ o) {
  int i = blockIdx.x * 256 + threadIdx.x;
  o[i] = a[i] + b[i];
}

// ---- gather + L2 normalize -> bf16 into A2 cols [0,512) ----
__global__ void k_gather(const float* __restrict__ feats, const int* __restrict__ topk,
                         bf16* __restrict__ A2) {
  int r = blockIdx.x;          // 0..19455
  int b = r / KSEL;
  int src = topk[r];
  const float4* row = (const float4*)(feats + ((size_t)b * SEQ + src) * DIN);
  int t = threadIdx.x;         // 128 threads
  float4 v = row[t];
  float ss = v.x * v.x + v.y * v.y + v.z * v.z + v.w * v.w;
#pragma unroll
  for (int o = 32; o > 0; o >>= 1) ss += __shfl_down(ss, o);
  __shared__ float wsum[2];
  if ((t & 63) == 0) wsum[t >> 6] = ss;
  __syncthreads();
  float total = wsum[0] + wsum[1];
  float inv = 1.0f / fmaxf(sqrtf(total), 1e-6f);
  bf16x4 o4;
  o4.x = (bf16)(v.x * inv);
  o4.y = (bf16)(v.y * inv);
  o4.z = (bf16)(v.z * inv);
  o4.w = (bf16)(v.w * inv);
  ((bf16x4*)A2)[(size_t)r * 256 + t] = o4;  // row stride 1024 bf16
}

// ---- m97-style bf16 GEMM: C = A(M x K, lda) @ Bt(N x K, ldb)^T + bias ----
__global__ __launch_bounds__(256, 3)
void k_gemm(const bf16* __restrict__ A, int lda, const bf16* __restrict__ Bt, int ldb,
            const float* __restrict__ bias, float* __restrict__ C, int ldc, int Kext) {
  __shared__ __align__(16) bf16 As[128 * 32];
  __shared__ __align__(16) bf16 Bs[128 * 32];
  const int m0 = blockIdx.y * 128, n0 = blockIdx.x * 128;
  const int tid = threadIdx.x, w = tid >> 6, lane = tid & 63;
  const int wr = (w >> 1) * 64, wc = (w & 1) * 64;
  const int srow = lane >> 2, scol = (lane & 3) * 8;
  bf16* as0 = &As[(w * 16) * 32];
  bf16* as1 = &As[(w * 16 + 64) * 32];
  bf16* bs0 = &Bs[(w * 16) * 32];
  bf16* bs1 = &Bs[(w * 16 + 64) * 32];
  const bf16* Ag0 = A + (size_t)(m0 + w * 16 + srow) * lda + scol;
  const bf16* Ag1 = Ag0 + (size_t)64 * lda;
  const bf16* Bg0 = Bt + (size_t)(n0 + w * 16 + srow) * ldb + scol;
  const bf16* Bg1 = Bg0 + (size_t)64 * ldb;
  f32x4 acc[4][4] = {};
  const int fr = lane & 15, fg = lane >> 4;
  for (int kt = 0; kt < Kext; kt += 32) {
    __syncthreads();
    gload16(Ag0 + kt, as0);
    gload16(Ag1 + kt, as1);
    gload16(Bg0 + kt, bs0);
    gload16(Bg1 + kt, bs1);
    __syncthreads();
    bf16x8 af[4], bfr[4];
#pragma unroll
    for (int i = 0; i < 4; ++i)
      af[i] = *(const bf16x8*)&As[(wr + i * 16 + fr) * 32 + fg * 8];
#pragma unroll
    for (int i = 0; i < 4; ++i)
      bfr[i] = *(const bf16x8*)&Bs[(wc + i * 16 + fr) * 32 + fg * 8];
#pragma unroll
    for (int i = 0; i < 4; ++i)
#pragma unroll
      for (int j = 0; j < 4; ++j)
        acc[i][j] = __builtin_amdgcn_mfma_f32_16x16x32_bf16(af[i], bfr[j], acc[i][j], 0, 0, 0);
  }
  float bv[4];
#pragma unroll
  for (int j = 0; j < 4; ++j) bv[j] = bias[n0 + wc + j * 16 + fr];
#pragma unroll
  for (int i = 0; i < 4; ++i) {
#pragma unroll
    for (int v = 0; v < 4; ++v) {
      int r = m0 + wr + i * 16 + fg * 4 + v;
      float* crow = C + (size_t)r * ldc + n0 + wc + fr;
#pragma unroll
      for (int j = 0; j < 4; ++j) crow[j * 16] = acc[i][j][v] + bv[j];
    }
  }
}

// ---- BN stats stage 1: per-128-row-block column sums / sumsq ----
__global__ void k_bnpart(const float* __restrict__ Hpre, float* __restrict__ part) {
  int blk = blockIdx.x, t = threadIdx.x;
  int c = t * 2;
  const float* p = Hpre + (size_t)blk * 128 * 512 + c;
  float s0 = 0, s1 = 0, q0 = 0, q1 = 0;
  for (int r = 0; r < 128; ++r) {
    float2 v = *(const float2*)(p + (size_t)r * 512);
    s0 += v.x; s1 += v.y;
    q0 += v.x * v.x; q1 += v.y * v.y;
  }
  part[blk * 512 + c] = s0;
  part[blk * 512 + c + 1] = s1;
  part[MTILES * 512 + blk * 512 + c] = q0;
  part[MTILES * 512 + blk * 512 + c + 1] = q1;
}

// ---- BN stats stage 2: scale/shift per column ----
__global__ void k_bnstats(const float* __restrict__ part, const float* __restrict__ g1,
                          const float* __restrict__ be1, float* __restrict__ bns) {
  int c = threadIdx.x;  // 512
  float s = 0, q = 0;
  for (int i = 0; i < MTILES; ++i) {
    s += part[i * 512 + c];
    q += part[MTILES * 512 + i * 512 + c];
  }
  const float invn = 1.0f / (float)MROWS;
  float mean = s * invn;
  float var = q * invn - mean * mean;  // biased, matches jnp.var
  float sc = rsqrtf(var + 1e-5f) * g1[c];
  bns[c] = sc;
  bns[512 + c] = be1[c] - mean * sc;
}

// ---- BN apply + ReLU -> bf16 into A2 cols [512,1024) ----
__global__ void k_bnapply(const float4* __restrict__ Hpre4, const float* __restrict__ bns,
                          bf16x4* __restrict__ A2h) {
  size_t idx = (size_t)blockIdx.x * 256 + threadIdx.x;  // 2,490,368 float4s
  float4 v = Hpre4[idx];
  int c4 = ((int)idx & 127) * 4;
  const float4 sc = *(const float4*)(bns + c4);
  const float4 sh = *(const float4*)(bns + 512 + c4);
  bf16x4 o;
  o.x = (bf16)fmaxf(fmaf(v.x, sc.x, sh.x), 0.0f);
  o.y = (bf16)fmaxf(fmaf(v.y, sc.y, sh.y), 0.0f);
  o.z = (bf16)fmaxf(fmaf(v.z, sc.z, sh.z), 0.0f);
  o.w = (bf16)fmaxf(fmaf(v.w, sc.w, sh.w), 0.0f);
  size_t row = idx >> 7;
  A2h[row * 256 + 128 + (idx & 127)] = o;
}

// ---- masked max-pool over first plen[b] of 76 rows ----
__global__ void k_pool(const float* __restrict__ fused, const int* __restrict__ plen,
                       float* __restrict__ out) {
  int b = blockIdx.x, t = threadIdx.x;  // 256 threads, 4 cols each
  int pl = plen[b];
  const float* base = fused + (size_t)b * KSEL * DEMB;
  float m[4] = {-__builtin_huge_valf(), -__builtin_huge_valf(),
                -__builtin_huge_valf(), -__builtin_huge_valf()};
  for (int j = 0; j < pl; ++j) {
#pragma unroll
    for (int q = 0; q < 4; ++q) m[q] = fmaxf(m[q], base[(size_t)j * DEMB + t + q * 256]);
  }
#pragma unroll
  for (int q = 0; q < 4; ++q) out[(size_t)b * DEMB + t + q * 256] = m[q];
}

extern "C" void kernel_launch(void* const* d_in, const int* in_sizes, int n_in,
                              void* d_out, int out_size, void* d_ws, size_t ws_size,
                              hipStream_t stream) {
  const float* features = (const float*)d_in[0];
  const int*   text     = (const int*)d_in[1];
  // d_in[2] = atten: provably unused (row eos is overwritten with -1 before use)
  const float* lin_w    = (const float*)d_in[3];
  const float* lin_b    = (const float*)d_in[4];
  const float* w1       = (const float*)d_in[5];
  const float* b1       = (const float*)d_in[6];
  const float* g1       = (const float*)d_in[7];
  const float* be1      = (const float*)d_in[8];
  const float* w2       = (const float*)d_in[9];
  const float* b2       = (const float*)d_in[10];
  float* out = (float*)d_out;
  char* ws = (char*)d_ws;

  // ws layout (bytes)
  int*   topk  = (int*)(ws + 0);           // 77,824
  int*   plen  = (int*)(ws + 77824);       // 1,024
  float* bns   = (float*)(ws + 78848);     // 4,096 (scale[512], shift[512])
  float* bias2 = (float*)(ws + 82944);     // 4,096
  float* part  = (float*)(ws + 87040);     // 622,592
  bf16*  w1t   = (bf16*)(ws + 709632);     // 524,288   (512 x 512)
  bf16*  b2t   = (bf16*)(ws + 1233920);    // 2,097,152 (1024 x 1024: [lin_w ; w2]^T)
  bf16*  A2    = (bf16*)(ws + 3331072);    // 39,845,888 (19456 x 1024: [X | H])
  float* hpre  = (float*)(ws + 43176960);  // 39.8 MB; reused as fused (79.7 MB)
  float* fused = hpre;

  k_prep<<<BSZ, 256, 0, stream>>>(text, topk, plen);
  k_transpose<<<dim3(16, 16), dim3(32, 8), 0, stream>>>(w1, w1t, 512, 512);
  k_transpose<<<dim3(32, 16), dim3(32, 8), 0, stream>>>(lin_w, b2t, 1024, 1024);
  k_transpose<<<dim3(32, 16), dim3(32, 8), 0, stream>>>(w2, b2t + 512, 1024, 1024);
  k_bias2<<<4, 256, 0, stream>>>(lin_b, b2, bias2);
  k_gather<<<MROWS, 128, 0, stream>>>(features, topk, A2);
  // Hpre = X @ w1 + b1   (19456 x 512, K=512)
  k_gemm<<<dim3(4, MTILES), 256, 0, stream>>>(A2, 1024, w1t, 512, b1, hpre, 512, 512);
  k_bnpart<<<MTILES, 256, 0, stream>>>(hpre, part);
  k_bnstats<<<1, 512, 0, stream>>>(part, g1, be1, bns);
  k_bnapply<<<9728, 256, 0, stream>>>((const float4*)hpre, bns, (bf16x4*)A2);
  // fused = [X|H] @ [lin_w ; w2] + (lin_b + b2)   (19456 x 1024, K=1024)
  k_gemm<<<dim3(8, MTILES), 256, 0, stream>>>(A2, 1024, b2t, 1024, bias2, fused, 1024, 1024);
  k_pool<<<BSZ, 256, 0, stream>>>(fused, plen, out);
}

// Round 2
// 137.263 us; speedup vs baseline: 1.2415x; 1.2415x over previous
//
#include <hip/hip_runtime.h>
#include <hip/hip_bf16.h>

typedef __bf16 bf16;
typedef __bf16 bf16x4 __attribute__((ext_vector_type(4)));
typedef __bf16 bf16x8 __attribute__((ext_vector_type(8)));
typedef float  f32x4  __attribute__((ext_vector_type(4)));

#define BSZ   256
#define SEQ   256
#define DIN   512
#define DEMB  1024
#define KSEL  76
#define MROWS (BSZ * KSEL)   // 19456
#define MTILES (MROWS / 128) // 152
#define PARTQ (MTILES * 512)

__device__ __forceinline__ void gload16(const void* g, void* l) {
  __builtin_amdgcn_global_load_lds((const __attribute__((address_space(1))) void*)g,
                                   (__attribute__((address_space(3))) void*)l, 16, 0, 0);
}

// monotone float<->uint order-preserving encode for atomicMax
__device__ __forceinline__ unsigned enc(float v) {
  unsigned u = __float_as_uint(v);
  return (u & 0x80000000u) ? ~u : (u | 0x80000000u);
}
__device__ __forceinline__ float dec(unsigned k) {
  return (k & 0x80000000u) ? __uint_as_float(k ^ 0x80000000u) : __uint_as_float(~k);
}

// ---- K0: token lengths -> closed-form top-k indices + pool lengths ----
// atten_sel[b,s] = -1 (s<len) / -0.0 (s>=len); lax.top_k ties -> lowest index
// first. So topk order = [len..255] then [0..] up to k=76.
__global__ void k_prep(const int* __restrict__ text, int* __restrict__ topk,
                       int* __restrict__ plen) {
  int b = blockIdx.x, t = threadIdx.x;
  __shared__ int red[256];
  red[t] = (text[b * SEQ + t] != 0) ? 1 : 0;
  __syncthreads();
  for (int s = 128; s > 0; s >>= 1) {
    if (t < s) red[t] += red[t + s];
    __syncthreads();
  }
  int len = red[0];
  int z = SEQ - len;  // count of -0.0 entries
  if (t < KSEL) topk[b * KSEL + t] = (t < z) ? (len + t) : (t - z);
  if (t == 0) {
    int p = len - 2;
    p = p < 1 ? 1 : (p > KSEL ? KSEL : p);
    plen[b] = p;
  }
}

// ---- weight transpose f32 (K x N) -> bf16 (N x K), row stride ldo ----
__global__ void k_transpose(const float* __restrict__ W, bf16* __restrict__ Wt,
                            int N, int ldo) {
  __shared__ float tile[32][33];
  int tx = threadIdx.x, ty = threadIdx.y;
  int n = blockIdx.x * 32 + tx;
  int k0 = blockIdx.y * 32;
#pragma unroll
  for (int r = 0; r < 32; r += 8)
    tile[ty + r][tx] = W[(size_t)(k0 + ty + r) * N + n];
  __syncthreads();
#pragma unroll
  for (int r = 0; r < 32; r += 8)
    Wt[(size_t)(blockIdx.x * 32 + ty + r) * ldo + k0 + tx] = (bf16)tile[tx][ty + r];
}

__global__ void k_bias2(const float* __restrict__ a, const float* __restrict__ b,
                        float* __restrict__ o) {
  int i = blockIdx.x * 256 + threadIdx.x;
  o[i] = a[i] + b[i];
}

// ---- gather + L2 normalize -> bf16 into A2 cols [0,512) ----
__global__ void k_gather(const float* __restrict__ feats, const int* __restrict__ topk,
                         bf16* __restrict__ A2) {
  int r = blockIdx.x;          // 0..19455
  int b = r / KSEL;
  int src = topk[r];
  const float4* row = (const float4*)(feats + ((size_t)b * SEQ + src) * DIN);
  int t = threadIdx.x;         // 128 threads
  float4 v = row[t];
  float ss = v.x * v.x + v.y * v.y + v.z * v.z + v.w * v.w;
#pragma unroll
  for (int o = 32; o > 0; o >>= 1) ss += __shfl_down(ss, o);
  __shared__ float wsum[2];
  if ((t & 63) == 0) wsum[t >> 6] = ss;
  __syncthreads();
  float total = wsum[0] + wsum[1];
  float inv = 1.0f / fmaxf(sqrtf(total), 1e-6f);
  bf16x4 o4;
  o4.x = (bf16)(v.x * inv);
  o4.y = (bf16)(v.y * inv);
  o4.z = (bf16)(v.z * inv);
  o4.w = (bf16)(v.w * inv);
  ((bf16x4*)A2)[(size_t)r * 256 + t] = o4;  // row stride 1024 bf16
}

// ---- BK=64 bf16 GEMM: C = A(M x K, lda) @ Bt(N x K, ldb)^T + bias ----
// LDS layout: [128 rows][64 cols] bf16, physical 16B-slot p of row R holds
// logical slot p ^ (R&7) (pre-swizzled global source, linear gload_lds dest,
// XOR-swizzled ds_read) -> minimum 8-lane/bank aliasing for ds_read_b128.
// EPI=1: write C + column BN partials (sum/sumsq) to part.
// EPI=2: no C write; masked per-batch max -> global atomicMax on enc() keys.
template<int EPI>
__global__ __launch_bounds__(256, 3)
void k_gemm(const bf16* __restrict__ A, int lda, const bf16* __restrict__ Bt, int ldb,
            const float* __restrict__ bias, float* __restrict__ C, int ldc, int Kext,
            float* __restrict__ part, const int* __restrict__ plen,
            unsigned* __restrict__ keys) {
  __shared__ __align__(16) bf16 As[128 * 64];
  __shared__ __align__(16) bf16 Bs[128 * 64];
  const int m0 = blockIdx.y * 128, n0 = blockIdx.x * 128;
  const int tid = threadIdx.x, w = tid >> 6, lane = tid & 63;
  const int wr = (w >> 1) * 64, wc = (w & 1) * 64;
  const int srow = lane >> 3;                 // 0..7 within an 8-row stage call
  const int scol = ((lane & 7) ^ srow) * 8;   // pre-swizzled source column
  const bf16* Ag = A + (size_t)(m0 + w * 32 + srow) * lda + scol;
  const bf16* Bg = Bt + (size_t)(n0 + w * 32 + srow) * ldb + scol;
  f32x4 acc[4][4] = {};
  const int fr = lane & 15, fg = lane >> 4;
  for (int kt = 0; kt < Kext; kt += 64) {
    __syncthreads();
#pragma unroll
    for (int c = 0; c < 4; ++c) {
      gload16(Ag + (size_t)(c * 8) * lda + kt, &As[(w * 32 + c * 8) * 64]);
      gload16(Bg + (size_t)(c * 8) * ldb + kt, &Bs[(w * 32 + c * 8) * 64]);
    }
    __syncthreads();
#pragma unroll
    for (int kk = 0; kk < 2; ++kk) {
      const int slot = ((kk << 2) | fg) ^ (fr & 7);
      bf16x8 af[4], bfr[4];
#pragma unroll
      for (int i = 0; i < 4; ++i)
        af[i] = *(const bf16x8*)&As[(wr + i * 16 + fr) * 64 + slot * 8];
#pragma unroll
      for (int j = 0; j < 4; ++j)
        bfr[j] = *(const bf16x8*)&Bs[(wc + j * 16 + fr) * 64 + slot * 8];
#pragma unroll
      for (int i = 0; i < 4; ++i)
#pragma unroll
        for (int j = 0; j < 4; ++j)
          acc[i][j] = __builtin_amdgcn_mfma_f32_16x16x32_bf16(af[i], bfr[j], acc[i][j], 0, 0, 0);
    }
  }
  float bv[4];
#pragma unroll
  for (int j = 0; j < 4; ++j) bv[j] = bias[n0 + wc + j * 16 + fr];

  if (EPI == 1) {
    float s[4] = {0, 0, 0, 0}, q[4] = {0, 0, 0, 0};
#pragma unroll
    for (int i = 0; i < 4; ++i)
#pragma unroll
      for (int v = 0; v < 4; ++v) {
        int r = m0 + wr + i * 16 + fg * 4 + v;
        float* crow = C + (size_t)r * ldc + n0 + wc + fr;
#pragma unroll
        for (int j = 0; j < 4; ++j) {
          float val = acc[i][j][v] + bv[j];
          crow[j * 16] = val;
          s[j] += val;
          q[j] += val * val;
        }
      }
    // deterministic reduce over fg (lanes +32, +16), then cross-wave via LDS
#pragma unroll
    for (int j = 0; j < 4; ++j) {
      s[j] += __shfl_down(s[j], 32); s[j] += __shfl_down(s[j], 16);
      q[j] += __shfl_down(q[j], 32); q[j] += __shfl_down(q[j], 16);
    }
    __syncthreads();
    float* red = (float*)As;  // 512 floats scratch: [w][j][fr] sums, +256 sq
    if (lane < 16) {
#pragma unroll
      for (int j = 0; j < 4; ++j) {
        red[(w * 4 + j) * 16 + lane] = s[j];
        red[256 + (w * 4 + j) * 16 + lane] = q[j];
      }
    }
    __syncthreads();
    if (tid < 128) {
      int c = tid;  // block-local column; waves {c>>6, (c>>6)+2} contributed
      int wsel = c >> 6, jj = (c >> 4) & 3, ff = c & 15;
      float ss = red[(wsel * 4 + jj) * 16 + ff] + red[((wsel + 2) * 4 + jj) * 16 + ff];
      float qq = red[256 + (wsel * 4 + jj) * 16 + ff] +
                 red[256 + ((wsel + 2) * 4 + jj) * 16 + ff];
      part[blockIdx.y * 512 + n0 + c] = ss;
      part[PARTQ + blockIdx.y * 512 + n0 + c] = qq;
    }
  } else {
    const float NEG = -__builtin_huge_valf();
    int cur_b = -1, pl = 0;
    bool any = false;
    float cm[4] = {NEG, NEG, NEG, NEG};
#pragma unroll
    for (int i = 0; i < 4; ++i)
#pragma unroll
      for (int v = 0; v < 4; ++v) {
        int gr = m0 + wr + i * 16 + fg * 4 + v;  // monotone over (i,v)
        int b = gr / KSEL;
        if (b != cur_b) {
          if (any) {
#pragma unroll
            for (int j = 0; j < 4; ++j)
              atomicMax(&keys[(size_t)cur_b * DEMB + n0 + wc + j * 16 + fr], enc(cm[j]));
          }
          cur_b = b;
          pl = plen[b];
          any = false;
#pragma unroll
          for (int j = 0; j < 4; ++j) cm[j] = NEG;
        }
        if (gr - b * KSEL < pl) {
          any = true;
#pragma unroll
          for (int j = 0; j < 4; ++j) cm[j] = fmaxf(cm[j], acc[i][j][v] + bv[j]);
        }
      }
    if (any) {
#pragma unroll
      for (int j = 0; j < 4; ++j)
        atomicMax(&keys[(size_t)cur_b * DEMB + n0 + wc + j * 16 + fr], enc(cm[j]));
    }
  }
}

// ---- BN stats stage 2: scale/shift per column ----
__global__ void k_bnstats(const float* __restrict__ part, const float* __restrict__ g1,
                          const float* __restrict__ be1, float* __restrict__ bns) {
  int c = threadIdx.x;  // 512
  float s = 0, q = 0;
  for (int i = 0; i < MTILES; ++i) {
    s += part[i * 512 + c];
    q += part[PARTQ + i * 512 + c];
  }
  const float invn = 1.0f / (float)MROWS;
  float mean = s * invn;
  float var = q * invn - mean * mean;  // biased, matches jnp.var
  float sc = rsqrtf(var + 1e-5f) * g1[c];
  bns[c] = sc;
  bns[512 + c] = be1[c] - mean * sc;
}

// ---- BN apply + ReLU -> bf16 into A2 cols [512,1024) ----
__global__ void k_bnapply(const float4* __restrict__ Hpre4, const float* __restrict__ bns,
                          bf16x4* __restrict__ A2h) {
  size_t idx = (size_t)blockIdx.x * 256 + threadIdx.x;  // 2,490,368 float4s
  float4 v = Hpre4[idx];
  int c4 = ((int)idx & 127) * 4;
  const float4 sc = *(const float4*)(bns + c4);
  const float4 sh = *(const float4*)(bns + 512 + c4);
  bf16x4 o;
  o.x = (bf16)fmaxf(fmaf(v.x, sc.x, sh.x), 0.0f);
  o.y = (bf16)fmaxf(fmaf(v.y, sc.y, sh.y), 0.0f);
  o.z = (bf16)fmaxf(fmaf(v.z, sc.z, sh.z), 0.0f);
  o.w = (bf16)fmaxf(fmaf(v.w, sc.w, sh.w), 0.0f);
  size_t row = idx >> 7;
  A2h[row * 256 + 128 + (idx & 127)] = o;
}

// ---- decode pooled keys -> f32 output ----
__global__ void k_decode(const unsigned* __restrict__ keys, float* __restrict__ out) {
  int i = blockIdx.x * 256 + threadIdx.x;
  out[i] = dec(keys[i]);
}

extern "C" void kernel_launch(void* const* d_in, const int* in_sizes, int n_in,
                              void* d_out, int out_size, void* d_ws, size_t ws_size,
                              hipStream_t stream) {
  const float* features = (const float*)d_in[0];
  const int*   text     = (const int*)d_in[1];
  // d_in[2] = atten: provably unused (row eos is overwritten with -1 before use)
  const float* lin_w    = (const float*)d_in[3];
  const float* lin_b    = (const float*)d_in[4];
  const float* w1       = (const float*)d_in[5];
  const float* b1       = (const float*)d_in[6];
  const float* g1       = (const float*)d_in[7];
  const float* be1      = (const float*)d_in[8];
  const float* w2       = (const float*)d_in[9];
  const float* b2       = (const float*)d_in[10];
  float* out = (float*)d_out;
  char* ws = (char*)d_ws;

  // ws layout (bytes)
  int*      topk  = (int*)(ws + 0);           // 77,824
  int*      plen  = (int*)(ws + 77824);       // 1,024
  float*    bns   = (float*)(ws + 78848);     // 4,096 (scale[512], shift[512])
  float*    bias2 = (float*)(ws + 82944);     // 4,096
  float*    part  = (float*)(ws + 87040);     // 622,592
  bf16*     w1t   = (bf16*)(ws + 709632);     // 524,288   (512 x 512)
  bf16*     b2t   = (bf16*)(ws + 1233920);    // 2,097,152 (1024 x 1024: [lin_w ; w2]^T)
  bf16*     A2    = (bf16*)(ws + 3331072);    // 39,845,888 (19456 x 1024: [X | H])
  float*    hpre  = (float*)(ws + 43176960);  // 39,845,888 (19456 x 512 f32)
  unsigned* keys  = (unsigned*)(ws + 83022848); // 1,048,576 (256 x 1024 u32)

  k_prep<<<BSZ, 256, 0, stream>>>(text, topk, plen);
  k_transpose<<<dim3(16, 16), dim3(32, 8), 0, stream>>>(w1, w1t, 512, 512);
  k_transpose<<<dim3(32, 16), dim3(32, 8), 0, stream>>>(lin_w, b2t, 1024, 1024);
  k_transpose<<<dim3(32, 16), dim3(32, 8), 0, stream>>>(w2, b2t + 512, 1024, 1024);
  k_bias2<<<4, 256, 0, stream>>>(lin_b, b2, bias2);
  hipMemsetAsync(keys, 0, BSZ * DEMB * sizeof(unsigned), stream);  // enc-space -inf
  k_gather<<<MROWS, 128, 0, stream>>>(features, topk, A2);
  // Hpre = X @ w1 + b1   (19456 x 512, K=512) + fused BN partial stats
  k_gemm<1><<<dim3(4, MTILES), 256, 0, stream>>>(A2, 1024, w1t, 512, b1, hpre, 512, 512,
                                                 part, nullptr, nullptr);
  k_bnstats<<<1, 512, 0, stream>>>(part, g1, be1, bns);
  k_bnapply<<<9728, 256, 0, stream>>>((const float4*)hpre, bns, (bf16x4*)A2);
  // [X|H] @ [lin_w ; w2] + (lin_b + b2), fused masked max-pool via atomicMax
  k_gemm<2><<<dim3(8, MTILES), 256, 0, stream>>>(A2, 1024, b2t, 1024, bias2, nullptr, 0,
                                                 1024, nullptr, plen, keys);
  k_decode<<<BSZ * DEMB / 256, 256, 0, stream>>>(keys, out);
}

// Round 3
// 131.575 us; speedup vs baseline: 1.2951x; 1.0432x over previous
//
#include <hip/hip_runtime.h>
#include <hip/hip_bf16.h>

typedef __bf16 bf16;
typedef __bf16 bf16x4 __attribute__((ext_vector_type(4)));
typedef __bf16 bf16x8 __attribute__((ext_vector_type(8)));
typedef float  f32x4  __attribute__((ext_vector_type(4)));

#define BSZ   256
#define SEQ   256
#define DIN   512
#define DEMB  1024
#define KSEL  76
#define MROWS (BSZ * KSEL)   // 19456
#define MTILES (MROWS / 128) // 152
#define PARTQ (MTILES * 512)

__device__ __forceinline__ void gload16(const void* g, void* l) {
  __builtin_amdgcn_global_load_lds((const __attribute__((address_space(1))) void*)g,
                                   (__attribute__((address_space(3))) void*)l, 16, 0, 0);
}

// monotone float<->uint order-preserving encode for atomicMax.
// All enc() values are > 0, so zero-init acts as the -inf sentinel
// (every key provably receives >=1 update since plen[b] >= 1).
__device__ __forceinline__ unsigned enc(float v) {
  unsigned u = __float_as_uint(v);
  return (u & 0x80000000u) ? ~u : (u | 0x80000000u);
}
__device__ __forceinline__ float dec(unsigned k) {
  return (k & 0x80000000u) ? __uint_as_float(k ^ 0x80000000u) : __uint_as_float(~k);
}

// ---- K0: token lengths -> closed-form top-k indices + pool lengths ----
// atten_sel[b,s] = -1 (s<len) / -0.0 (s>=len); lax.top_k ties -> lowest index
// first. So topk order = [len..255] then [0..] up to k=76.
// Also zero-inits the pooled-max key buffer (replaces slow runtime fill).
__global__ void k_prep(const int* __restrict__ text, int* __restrict__ topk,
                       int* __restrict__ plen, uint4* __restrict__ keys4) {
  int b = blockIdx.x, t = threadIdx.x;
  keys4[b * 256 + t] = make_uint4(0u, 0u, 0u, 0u);
  __shared__ int red[256];
  red[t] = (text[b * SEQ + t] != 0) ? 1 : 0;
  __syncthreads();
  for (int s = 128; s > 0; s >>= 1) {
    if (t < s) red[t] += red[t + s];
    __syncthreads();
  }
  int len = red[0];
  int z = SEQ - len;  // count of -0.0 entries
  if (t < KSEL) topk[b * KSEL + t] = (t < z) ? (len + t) : (t - z);
  if (t == 0) {
    int p = len - 2;
    p = p < 1 ? 1 : (p > KSEL ? KSEL : p);
    plen[b] = p;
  }
}

// ---- weight transpose f32 (K x N) -> bf16 (N x K), row stride ldo ----
__global__ void k_transpose(const float* __restrict__ W, bf16* __restrict__ Wt,
                            int N, int ldo) {
  __shared__ float tile[32][33];
  int tx = threadIdx.x, ty = threadIdx.y;
  int n = blockIdx.x * 32 + tx;
  int k0 = blockIdx.y * 32;
#pragma unroll
  for (int r = 0; r < 32; r += 8)
    tile[ty + r][tx] = W[(size_t)(k0 + ty + r) * N + n];
  __syncthreads();
#pragma unroll
  for (int r = 0; r < 32; r += 8)
    Wt[(size_t)(blockIdx.x * 32 + ty + r) * ldo + k0 + tx] = (bf16)tile[tx][ty + r];
}

__global__ void k_bias2(const float* __restrict__ a, const float* __restrict__ b,
                        float* __restrict__ o) {
  int i = blockIdx.x * 256 + threadIdx.x;
  o[i] = a[i] + b[i];
}

// ---- gather + L2 normalize -> bf16 into A2 cols [0,512) ----
__global__ void k_gather(const float* __restrict__ feats, const int* __restrict__ topk,
                         bf16* __restrict__ A2) {
  int r = blockIdx.x;          // 0..19455
  int b = r / KSEL;
  int src = topk[r];
  const float4* row = (const float4*)(feats + ((size_t)b * SEQ + src) * DIN);
  int t = threadIdx.x;         // 128 threads
  float4 v = row[t];
  float ss = v.x * v.x + v.y * v.y + v.z * v.z + v.w * v.w;
#pragma unroll
  for (int o = 32; o > 0; o >>= 1) ss += __shfl_down(ss, o);
  __shared__ float wsum[2];
  if ((t & 63) == 0) wsum[t >> 6] = ss;
  __syncthreads();
  float total = wsum[0] + wsum[1];
  float inv = 1.0f / fmaxf(sqrtf(total), 1e-6f);
  bf16x4 o4;
  o4.x = (bf16)(v.x * inv);
  o4.y = (bf16)(v.y * inv);
  o4.z = (bf16)(v.z * inv);
  o4.w = (bf16)(v.w * inv);
  ((bf16x4*)A2)[(size_t)r * 256 + t] = o4;  // row stride 1024 bf16
}

// ---- BK=64 bf16 GEMM: A(M x K, lda) @ Bt(N x K, ldb)^T + bias ----
// LDS layout: [128 rows][64 cols] bf16, physical 16B-slot p of row R holds
// logical slot p ^ (R&7) (pre-swizzled global source, linear gload_lds dest,
// XOR-swizzled ds_read) -> minimum 8-lane/bank aliasing for ds_read_b128.
// EPI=1: write bf16 result into Cb (A2 H-half) + column BN partials to part.
// EPI=2: no C write; masked per-batch max -> global atomicMax on enc() keys.
template<int EPI>
__global__ __launch_bounds__(256, 3)
void k_gemm(const bf16* __restrict__ A, int lda, const bf16* __restrict__ Bt, int ldb,
            const float* __restrict__ bias, bf16* __restrict__ Cb, int ldc, int Kext,
            float* __restrict__ part, const int* __restrict__ plen,
            unsigned* __restrict__ keys) {
  __shared__ __align__(16) bf16 As[128 * 64];
  __shared__ __align__(16) bf16 Bs[128 * 64];
  const int m0 = blockIdx.y * 128, n0 = blockIdx.x * 128;
  const int tid = threadIdx.x, w = tid >> 6, lane = tid & 63;
  const int wr = (w >> 1) * 64, wc = (w & 1) * 64;
  const int srow = lane >> 3;                 // 0..7 within an 8-row stage call
  const int scol = ((lane & 7) ^ srow) * 8;   // pre-swizzled source column
  const bf16* Ag = A + (size_t)(m0 + w * 32 + srow) * lda + scol;
  const bf16* Bg = Bt + (size_t)(n0 + w * 32 + srow) * ldb + scol;
  f32x4 acc[4][4] = {};
  const int fr = lane & 15, fg = lane >> 4;
  for (int kt = 0; kt < Kext; kt += 64) {
    __syncthreads();
#pragma unroll
    for (int c = 0; c < 4; ++c) {
      gload16(Ag + (size_t)(c * 8) * lda + kt, &As[(w * 32 + c * 8) * 64]);
      gload16(Bg + (size_t)(c * 8) * ldb + kt, &Bs[(w * 32 + c * 8) * 64]);
    }
    __syncthreads();
#pragma unroll
    for (int kk = 0; kk < 2; ++kk) {
      const int slot = ((kk << 2) | fg) ^ (fr & 7);
      bf16x8 af[4], bfr[4];
#pragma unroll
      for (int i = 0; i < 4; ++i)
        af[i] = *(const bf16x8*)&As[(wr + i * 16 + fr) * 64 + slot * 8];
#pragma unroll
      for (int j = 0; j < 4; ++j)
        bfr[j] = *(const bf16x8*)&Bs[(wc + j * 16 + fr) * 64 + slot * 8];
#pragma unroll
      for (int i = 0; i < 4; ++i)
#pragma unroll
        for (int j = 0; j < 4; ++j)
          acc[i][j] = __builtin_amdgcn_mfma_f32_16x16x32_bf16(af[i], bfr[j], acc[i][j], 0, 0, 0);
    }
  }
  float bv[4];
#pragma unroll
  for (int j = 0; j < 4; ++j) bv[j] = bias[n0 + wc + j * 16 + fr];

  if (EPI == 1) {
    float s[4] = {0, 0, 0, 0}, q[4] = {0, 0, 0, 0};
#pragma unroll
    for (int i = 0; i < 4; ++i)
#pragma unroll
      for (int v = 0; v < 4; ++v) {
        int r = m0 + wr + i * 16 + fg * 4 + v;
        bf16* crow = Cb + (size_t)r * ldc + n0 + wc + fr;
#pragma unroll
        for (int j = 0; j < 4; ++j) {
          float val = acc[i][j][v] + bv[j];
          crow[j * 16] = (bf16)val;      // bf16 h_pre into A2 H-half
          s[j] += val;                   // stats stay f32-exact
          q[j] += val * val;
        }
      }
    // deterministic reduce over fg (lanes +32, +16), then cross-wave via LDS
#pragma unroll
    for (int j = 0; j < 4; ++j) {
      s[j] += __shfl_down(s[j], 32); s[j] += __shfl_down(s[j], 16);
      q[j] += __shfl_down(q[j], 32); q[j] += __shfl_down(q[j], 16);
    }
    __syncthreads();
    float* red = (float*)As;  // 512 floats scratch: [w][j][fr] sums, +256 sq
    if (lane < 16) {
#pragma unroll
      for (int j = 0; j < 4; ++j) {
        red[(w * 4 + j) * 16 + lane] = s[j];
        red[256 + (w * 4 + j) * 16 + lane] = q[j];
      }
    }
    __syncthreads();
    if (tid < 128) {
      int c = tid;  // block-local column; waves {c>>6, (c>>6)+2} contributed
      int wsel = c >> 6, jj = (c >> 4) & 3, ff = c & 15;
      float ss = red[(wsel * 4 + jj) * 16 + ff] + red[((wsel + 2) * 4 + jj) * 16 + ff];
      float qq = red[256 + (wsel * 4 + jj) * 16 + ff] +
                 red[256 + ((wsel + 2) * 4 + jj) * 16 + ff];
      part[blockIdx.y * 512 + n0 + c] = ss;
      part[PARTQ + blockIdx.y * 512 + n0 + c] = qq;
    }
  } else {
    const float NEG = -__builtin_huge_valf();
    int cur_b = -1, pl = 0;
    bool any = false;
    float cm[4] = {NEG, NEG, NEG, NEG};
#pragma unroll
    for (int i = 0; i < 4; ++i)
#pragma unroll
      for (int v = 0; v < 4; ++v) {
        int gr = m0 + wr + i * 16 + fg * 4 + v;  // monotone over (i,v)
        int b = gr / KSEL;
        if (b != cur_b) {
          if (any) {
#pragma unroll
            for (int j = 0; j < 4; ++j)
              atomicMax(&keys[(size_t)cur_b * DEMB + n0 + wc + j * 16 + fr], enc(cm[j]));
          }
          cur_b = b;
          pl = plen[b];
          any = false;
#pragma unroll
          for (int j = 0; j < 4; ++j) cm[j] = NEG;
        }
        if (gr - b * KSEL < pl) {
          any = true;
#pragma unroll
          for (int j = 0; j < 4; ++j) cm[j] = fmaxf(cm[j], acc[i][j][v] + bv[j]);
        }
      }
    if (any) {
#pragma unroll
      for (int j = 0; j < 4; ++j)
        atomicMax(&keys[(size_t)cur_b * DEMB + n0 + wc + j * 16 + fr], enc(cm[j]));
    }
  }
}

// ---- BN stats stage 2: scale/shift per column ----
__global__ void k_bnstats(const float* __restrict__ part, const float* __restrict__ g1,
                          const float* __restrict__ be1, float* __restrict__ bns) {
  int c = threadIdx.x;  // 512
  float s = 0, q = 0;
  for (int i = 0; i < MTILES; ++i) {
    s += part[i * 512 + c];
    q += part[PARTQ + i * 512 + c];
  }
  const float invn = 1.0f / (float)MROWS;
  float mean = s * invn;
  float var = q * invn - mean * mean;  // biased, matches jnp.var
  float sc = rsqrtf(var + 1e-5f) * g1[c];
  bns[c] = sc;
  bns[512 + c] = be1[c] - mean * sc;
}

// ---- BN apply + ReLU, in place on A2 cols [512,1024) (bf16) ----
__global__ void k_bnapply(bf16x8* __restrict__ A2v, const float* __restrict__ bns) {
  size_t idx = (size_t)blockIdx.x * 256 + threadIdx.x;  // 1,245,184 chunks
  size_t row = idx >> 6;
  int c = (int)(idx & 63);                 // 8-col chunk within H half
  bf16x8* p = A2v + row * 128 + 64 + c;    // row stride 1024 bf16 = 128 chunks
  bf16x8 v = *p;
  int c8 = c * 8;
  const float4 s0 = *(const float4*)(bns + c8);
  const float4 s1 = *(const float4*)(bns + c8 + 4);
  const float4 h0 = *(const float4*)(bns + 512 + c8);
  const float4 h1 = *(const float4*)(bns + 512 + c8 + 4);
  bf16x8 o;
  o[0] = (bf16)fmaxf(fmaf((float)v[0], s0.x, h0.x), 0.0f);
  o[1] = (bf16)fmaxf(fmaf((float)v[1], s0.y, h0.y), 0.0f);
  o[2] = (bf16)fmaxf(fmaf((float)v[2], s0.z, h0.z), 0.0f);
  o[3] = (bf16)fmaxf(fmaf((float)v[3], s0.w, h0.w), 0.0f);
  o[4] = (bf16)fmaxf(fmaf((float)v[4], s1.x, h1.x), 0.0f);
  o[5] = (bf16)fmaxf(fmaf((float)v[5], s1.y, h1.y), 0.0f);
  o[6] = (bf16)fmaxf(fmaf((float)v[6], s1.z, h1.z), 0.0f);
  o[7] = (bf16)fmaxf(fmaf((float)v[7], s1.w, h1.w), 0.0f);
  *p = o;
}

// ---- decode pooled keys -> f32 output ----
__global__ void k_decode(const unsigned* __restrict__ keys, float* __restrict__ out) {
  int i = blockIdx.x * 256 + threadIdx.x;
  out[i] = dec(keys[i]);
}

extern "C" void kernel_launch(void* const* d_in, const int* in_sizes, int n_in,
                              void* d_out, int out_size, void* d_ws, size_t ws_size,
                              hipStream_t stream) {
  const float* features = (const float*)d_in[0];
  const int*   text     = (const int*)d_in[1];
  // d_in[2] = atten: provably unused (row eos is overwritten with -1 before use)
  const float* lin_w    = (const float*)d_in[3];
  const float* lin_b    = (const float*)d_in[4];
  const float* w1       = (const float*)d_in[5];
  const float* b1       = (const float*)d_in[6];
  const float* g1       = (const float*)d_in[7];
  const float* be1      = (const float*)d_in[8];
  const float* w2       = (const float*)d_in[9];
  const float* b2       = (const float*)d_in[10];
  float* out = (float*)d_out;
  char* ws = (char*)d_ws;

  // ws layout (bytes)
  int*      topk  = (int*)(ws + 0);           // 77,824
  int*      plen  = (int*)(ws + 77824);       // 1,024
  float*    bns   = (float*)(ws + 78848);     // 4,096 (scale[512], shift[512])
  float*    bias2 = (float*)(ws + 82944);     // 4,096
  float*    part  = (float*)(ws + 87040);     // 622,592
  bf16*     w1t   = (bf16*)(ws + 709632);     // 524,288   (512 x 512)
  bf16*     b2t   = (bf16*)(ws + 1233920);    // 2,097,152 (1024 x 1024: [lin_w ; w2]^T)
  bf16*     A2    = (bf16*)(ws + 3331072);    // 39,845,888 (19456 x 1024: [X | H])
  unsigned* keys  = (unsigned*)(ws + 43176960); // 1,048,576 (256 x 1024 u32)

  k_prep<<<BSZ, 256, 0, stream>>>(text, topk, plen, (uint4*)keys);
  k_transpose<<<dim3(16, 16), dim3(32, 8), 0, stream>>>(w1, w1t, 512, 512);
  k_transpose<<<dim3(32, 16), dim3(32, 8), 0, stream>>>(lin_w, b2t, 1024, 1024);
  k_transpose<<<dim3(32, 16), dim3(32, 8), 0, stream>>>(w2, b2t + 512, 1024, 1024);
  k_bias2<<<4, 256, 0, stream>>>(lin_b, b2, bias2);
  k_gather<<<MROWS, 128, 0, stream>>>(features, topk, A2);
  // H_pre = X @ w1 + b1 -> bf16 into A2[:,512:1024], + fused BN partial stats
  k_gemm<1><<<dim3(4, MTILES), 256, 0, stream>>>(A2, 1024, w1t, 512, b1, A2 + 512, 1024,
                                                 512, part, nullptr, nullptr);
  k_bnstats<<<1, 512, 0, stream>>>(part, g1, be1, bns);
  k_bnapply<<<4864, 256, 0, stream>>>((bf16x8*)A2, bns);
  // [X|H] @ [lin_w ; w2] + (lin_b + b2), fused masked max-pool via atomicMax
  k_gemm<2><<<dim3(8, MTILES), 256, 0, stream>>>(A2, 1024, b2t, 1024, bias2, nullptr, 0,
                                                 1024, nullptr, plen, keys);
  k_decode<<<BSZ * DEMB / 256, 256, 0, stream>>>(keys, out);
}